// Round 9
// baseline (292.673 us; speedup 1.0000x reference)
//
#include <hip/hip_runtime.h>
#include <cstddef>

// Problem constants (fixed by the reference)
constexpr int Bn = 2048;   // batch
constexpr int In = 4096;   // rated items
constexpr int Dn = 512;    // embedding dim

typedef _Float16 f16;
typedef _Float16 f16x8 __attribute__((ext_vector_type(8)));
typedef float    f32x4 __attribute__((ext_vector_type(4)));

// ---------------------------------------------------------------------------
// rs[i] = rated_items[i,:] . att_w[D:2D]  (per-item attention logit).
// ---------------------------------------------------------------------------
__global__ __launch_bounds__(256) void k_rs(const float* __restrict__ rated,
                                            const float* __restrict__ att_w,
                                            float* __restrict__ rs) {
  const int wid  = threadIdx.x >> 6;
  const int lane = threadIdx.x & 63;
  const int i = blockIdx.x * 4 + wid;
  const float* row = rated + (size_t)i * Dn;
  const float* wr  = att_w + Dn;
  float s = 0.f;
  #pragma unroll
  for (int d = 0; d < Dn / 64; ++d)
    s = fmaf(row[lane + d * 64], wr[lane + d * 64], s);
  #pragma unroll
  for (int off = 32; off > 0; off >>= 1) s += __shfl_down(s, off);
  if (lane == 0) rs[i] = s;
}

// ---------------------------------------------------------------------------
// Dense fp16 attention-weight row:
//   w[b][i] = um!=0 ? exp(rs[i]-m_b)*um[b][i] / S_b : 0,  S_b = SUM exp(rs-m)
// ---------------------------------------------------------------------------
__global__ __launch_bounds__(256) void k_att(const float* __restrict__ um,
                                             const float* __restrict__ rs,
                                             f16* __restrict__ att) {
  __shared__ float t[In];
  __shared__ float red[4];
  const int tid = threadIdx.x;
  const int b = blockIdx.x;
  const float* umrow = um + (size_t)b * In;

  float ua[16];
  float lmax = -INFINITY;
  #pragma unroll
  for (int it = 0; it < 4; ++it) {
    const int i = (it * 256 + tid) * 4;
    const float4 v = *reinterpret_cast<const float4*>(umrow + i);
    ua[it * 4 + 0] = v.x; ua[it * 4 + 1] = v.y;
    ua[it * 4 + 2] = v.z; ua[it * 4 + 3] = v.w;
    #pragma unroll
    for (int j = 0; j < 4; ++j) {
      if (ua[it * 4 + j] != 0.f) {
        const float r = rs[i + j];
        t[i + j] = r;
        lmax = fmaxf(lmax, r);
      } else {
        t[i + j] = -INFINITY;
      }
    }
  }
  #pragma unroll
  for (int off = 32; off > 0; off >>= 1) lmax = fmaxf(lmax, __shfl_down(lmax, off));
  if ((tid & 63) == 0) red[tid >> 6] = lmax;
  __syncthreads();
  const float m = fmaxf(fmaxf(red[0], red[1]), fmaxf(red[2], red[3]));
  __syncthreads();

  float lsum = 0.f;
  #pragma unroll
  for (int it = 0; it < 4; ++it) {
    const int i = (it * 256 + tid) * 4;
    #pragma unroll
    for (int j = 0; j < 4; ++j) {
      float v = 0.f;
      if (ua[it * 4 + j] != 0.f) {
        const float e = __expf(t[i + j] - m);
        lsum += e;                    // denominator: plain exp sum (r6 bug fix)
        v = e * ua[it * 4 + j];
      }
      t[i + j] = v;
    }
  }
  #pragma unroll
  for (int off = 32; off > 0; off >>= 1) lsum += __shfl_down(lsum, off);
  if ((tid & 63) == 0) red[tid >> 6] = lsum;
  __syncthreads();
  const float S = red[0] + red[1] + red[2] + red[3];
  const float inv = (S > 0.f) ? 1.0f / S : 0.0f;

  f16* arow = att + (size_t)b * In;
  #pragma unroll
  for (int it = 0; it < 2; ++it) {
    const int i = (it * 256 + tid) * 8;
    f16x8 h;
    #pragma unroll
    for (int j = 0; j < 8; ++j) h[j] = (f16)(t[i + j] * inv);
    *reinterpret_cast<f16x8*>(arow + i) = h;
  }
}

// ---------------------------------------------------------------------------
// Weight prep: src[K][N] fp32 -> dst[N][K] fp16 (transpose), 32x32 LDS tiles.
// ---------------------------------------------------------------------------
__global__ __launch_bounds__(256) void k_transpose_f2h(const float* __restrict__ src,
                                                       f16* __restrict__ dst,
                                                       int K, int N) {
  __shared__ float tile[32][33];
  const int tx = threadIdx.x & 31;
  const int ty = threadIdx.x >> 5;
  const int n0 = blockIdx.x * 32;
  const int k0 = blockIdx.y * 32;
  #pragma unroll
  for (int i = 0; i < 4; ++i)
    tile[ty + i * 8][tx] = src[(size_t)(k0 + ty + i * 8) * N + n0 + tx];
  __syncthreads();
  #pragma unroll
  for (int i = 0; i < 4; ++i)
    dst[(size_t)(n0 + ty + i * 8) * K + k0 + tx] = (f16)tile[tx][ty + i * 8];
}

// Plain fp32 -> fp16 cast. n multiple of 1024.
__global__ __launch_bounds__(256) void k_cast_f2h(const float* __restrict__ src,
                                                  f16* __restrict__ dst, int n) {
  const int i = (blockIdx.x * 256 + threadIdx.x) * 4;
  if (i < n) {
    const float4 v = *reinterpret_cast<const float4*>(src + i);
    f16 h0 = (f16)v.x, h1 = (f16)v.y, h2 = (f16)v.z, h3 = (f16)v.w;
    f16* p = dst + i;
    p[0] = h0; p[1] = h1; p[2] = h2; p[3] = h3;
  }
}

// ---------------------------------------------------------------------------
// Grouped / split-K MFMA GEMM.  Inner loop byte-identical to the verified
// round-7/8 kernel (64x64 tile, BK=64, 4 waves, 2x2 frags/wave, reg prefetch).
// Each dispatch carries up to two independent problems (A then B, switched on
// blockIdx); each problem may be K-split into `splits` slices of Kc, writing
// fp32 partials to P (reduced by k_reduce). M is fixed at 2048 (32 m-tiles).
// Round-8 profile: 256-wg layers ran 1 block/CU (Occupancy 5%) -> grouping +
// split-K raises every dispatch to >=512 wg for multi-block co-residency.
// ---------------------------------------------------------------------------
struct GemmDesc {
  const f16* A;        // M x K row-major
  const f16* Wt;       // N x K row-major
  const float* bias;   // nullptr -> no bias (direct-store path only)
  f16* C;              // fp16 output (if P == nullptr)
  float* P;            // fp32 partials [splits][2048][N] (if non-null)
  int N, K, Kc, ldc, nTilesN, relu;
};

__global__ __launch_bounds__(256) void k_mgemm(GemmDesc dA, GemmDesc dB, int bSplit) {
  const bool second = ((int)blockIdx.x >= bSplit);
  const GemmDesc d = second ? dB : dA;
  const int local = second ? (int)blockIdx.x - bSplit : (int)blockIdx.x;

  const int bm = (local & 31) * 64;            // 32 m-tiles (M=2048)
  const int rest = local >> 5;
  const int bn = (rest % d.nTilesN) * 64;
  const int ks = rest / d.nTilesN;
  const int kBeg = ks * d.Kc;

  __shared__ __align__(16) f16 As[64][72];
  __shared__ __align__(16) f16 Bs[64][72];

  const int tid  = threadIdx.x;
  const int lane = tid & 63;
  const int wave = tid >> 6;
  const int wrow = (wave >> 1) * 32;
  const int wcol = (wave & 1) * 32;
  const int lrow = lane & 15;
  const int koff = (lane >> 4) * 8;

  const int r = tid >> 2;
  const int c = (tid & 3) * 16;

  const f16* pa = d.A  + (size_t)(bm + r) * d.K + kBeg + c;
  const f16* pb = d.Wt + (size_t)(bn + r) * d.K + kBeg + c;

  f16x8 ra0, ra1, rb0, rb1;
  #define LOADG()                                                   \
    ra0 = *reinterpret_cast<const f16x8*>(pa + 0);                  \
    ra1 = *reinterpret_cast<const f16x8*>(pa + 8);                  \
    rb0 = *reinterpret_cast<const f16x8*>(pb + 0);                  \
    rb1 = *reinterpret_cast<const f16x8*>(pb + 8);

  f32x4 acc[2][2] = {};

  LOADG();
  for (int k0 = 0; k0 < d.Kc; k0 += 64) {
    *reinterpret_cast<f16x8*>(&As[r][c + 0]) = ra0;
    *reinterpret_cast<f16x8*>(&As[r][c + 8]) = ra1;
    *reinterpret_cast<f16x8*>(&Bs[r][c + 0]) = rb0;
    *reinterpret_cast<f16x8*>(&Bs[r][c + 8]) = rb1;
    __syncthreads();

    if (k0 + 64 < d.Kc) {          // prefetch next K-tile
      pa += 64; pb += 64;
      LOADG();
    }

    #pragma unroll
    for (int kss = 0; kss < 2; ++kss) {
      const int kk = kss * 32 + koff;
      const f16x8 a0 = *reinterpret_cast<const f16x8*>(&As[wrow +  0 + lrow][kk]);
      const f16x8 a1 = *reinterpret_cast<const f16x8*>(&As[wrow + 16 + lrow][kk]);
      const f16x8 b0 = *reinterpret_cast<const f16x8*>(&Bs[wcol +  0 + lrow][kk]);
      const f16x8 b1 = *reinterpret_cast<const f16x8*>(&Bs[wcol + 16 + lrow][kk]);

      acc[0][0] = __builtin_amdgcn_mfma_f32_16x16x32_f16(a0, b0, acc[0][0], 0, 0, 0);
      acc[0][1] = __builtin_amdgcn_mfma_f32_16x16x32_f16(a0, b1, acc[0][1], 0, 0, 0);
      acc[1][0] = __builtin_amdgcn_mfma_f32_16x16x32_f16(a1, b0, acc[1][0], 0, 0, 0);
      acc[1][1] = __builtin_amdgcn_mfma_f32_16x16x32_f16(a1, b1, acc[1][1], 0, 0, 0);
    }
    __syncthreads();
  }
  #undef LOADG

  // epilogue (C/D map: col=lane&15, row=(lane>>4)*4+reg — HW-verified)
  const int orow = (lane >> 4) * 4;
  if (d.P) {
    float* pp = d.P + (size_t)ks * ((size_t)2048 * d.N);
    #pragma unroll
    for (int mf = 0; mf < 2; ++mf)
      #pragma unroll
      for (int nf = 0; nf < 2; ++nf) {
        const int col = bn + wcol + nf * 16 + lrow;
        #pragma unroll
        for (int rr = 0; rr < 4; ++rr) {
          const int row = bm + wrow + mf * 16 + orow + rr;
          pp[(size_t)row * d.N + col] = acc[mf][nf][rr];
        }
      }
  } else {
    #pragma unroll
    for (int mf = 0; mf < 2; ++mf)
      #pragma unroll
      for (int nf = 0; nf < 2; ++nf) {
        const int col = bn + wcol + nf * 16 + lrow;
        const float bv = d.bias ? d.bias[col] : 0.f;
        #pragma unroll
        for (int rr = 0; rr < 4; ++rr) {
          const int row = bm + wrow + mf * 16 + orow + rr;
          float v = acc[mf][nf][rr] + bv;
          if (d.relu) v = fmaxf(v, 0.f);
          d.C[(size_t)row * d.ldc + col] = (f16)v;
        }
      }
  }
}

// ---------------------------------------------------------------------------
// Sum S fp32 partial planes + bias + ReLU -> fp16 (memory-bound, 8 elem/thr).
// ---------------------------------------------------------------------------
__global__ __launch_bounds__(256) void k_reduce(const float* __restrict__ P,
                                                int S, int MN, int N,
                                                const float* __restrict__ bias,
                                                int relu, f16* __restrict__ C,
                                                int ldc) {
  const int idx = (blockIdx.x * 256 + threadIdx.x) * 8;
  float v[8];
  {
    const float4 a0 = *reinterpret_cast<const float4*>(P + idx);
    const float4 a1 = *reinterpret_cast<const float4*>(P + idx + 4);
    v[0] = a0.x; v[1] = a0.y; v[2] = a0.z; v[3] = a0.w;
    v[4] = a1.x; v[5] = a1.y; v[6] = a1.z; v[7] = a1.w;
  }
  for (int s = 1; s < S; ++s) {
    const float* ps = P + (size_t)s * MN + idx;
    const float4 b0 = *reinterpret_cast<const float4*>(ps);
    const float4 b1 = *reinterpret_cast<const float4*>(ps + 4);
    v[0] += b0.x; v[1] += b0.y; v[2] += b0.z; v[3] += b0.w;
    v[4] += b1.x; v[5] += b1.y; v[6] += b1.z; v[7] += b1.w;
  }
  const int row = idx / N;
  const int col = idx % N;
  f16x8 h;
  #pragma unroll
  for (int j = 0; j < 8; ++j) {
    float x = v[j] + (bias ? bias[col + j] : 0.f);
    if (relu) x = fmaxf(x, 0.f);
    h[j] = (f16)x;
  }
  *reinterpret_cast<f16x8*>(C + (size_t)row * ldc + col) = h;
}

// ---------------------------------------------------------------------------
// out[b] = h3[b,:256] . mw4 + mb4
// ---------------------------------------------------------------------------
__global__ __launch_bounds__(256) void k_final(const f16* __restrict__ h3,
                                               const float* __restrict__ mw4,
                                               const float* __restrict__ mb4,
                                               float* __restrict__ out) {
  const int wid = threadIdx.x >> 6;
  const int lane = threadIdx.x & 63;
  const int row = blockIdx.x * 4 + wid;
  const f16* hr = h3 + (size_t)row * 256;
  float s = 0.f;
  #pragma unroll
  for (int d = 0; d < 4; ++d)
    s = fmaf((float)hr[lane + d * 64], mw4[lane + d * 64], s);
  #pragma unroll
  for (int off = 32; off > 0; off >>= 1) s += __shfl_down(s, off);
  if (lane == 0) out[row] = s + mb4[0];
}

// ---------------------------------------------------------------------------
extern "C" void kernel_launch(void* const* d_in, const int* in_sizes, int n_in,
                              void* d_out, int out_size, void* d_ws, size_t ws_size,
                              hipStream_t stream) {
  const float* cand  = (const float*)d_in[0];
  const float* rated = (const float*)d_in[1];
  const float* um    = (const float*)d_in[2];
  const float* att_w = (const float*)d_in[3];
  const float* iw1 = (const float*)d_in[5];
  const float* ib1 = (const float*)d_in[6];
  const float* iw2 = (const float*)d_in[7];
  const float* ib2 = (const float*)d_in[8];
  const float* uw1 = (const float*)d_in[9];
  const float* ub1 = (const float*)d_in[10];
  const float* uw2 = (const float*)d_in[11];
  const float* ub2 = (const float*)d_in[12];
  const float* mw1 = (const float*)d_in[13];
  const float* mb1 = (const float*)d_in[14];
  const float* mw2 = (const float*)d_in[15];
  const float* mb2 = (const float*)d_in[16];
  const float* mw3 = (const float*)d_in[17];
  const float* mb3 = (const float*)d_in[18];
  const float* mw4 = (const float*)d_in[19];
  const float* mb4 = (const float*)d_in[20];
  float* out = (float*)d_out;

  // ---- workspace layout (fp16 element units); ~57 MB total ----
  f16*   hws = (f16*)d_ws;
  float* rs  = (float*)d_ws;            // 4096 fp32 = 8192 half-slots
  size_t off = 8192;
  auto take = [&](size_t n) { f16* p = hws + off; off += n; return p; };
  f16* t_iw1   = take(512 * 1024);
  f16* t_iw2   = take(1024 * 512);
  f16* t_uw1   = take(512 * 2048);
  f16* t_uw2   = take(2048 * 1024);
  f16* t_mw1   = take(1536 * 1024);
  f16* t_mw2   = take(1024 * 512);
  f16* t_mw3   = take(512 * 256);
  f16* t_rated = take(512 * 4096);
  f16* cand_h  = take(2048 * 512);
  f16* uf_h    = take(2048 * 512);
  f16* big     = take(2048 * 2048);     // att_d head / h_u1 / h_m1
  f16* Xc      = take(2048 * 1536);     // concat [item_emb | user_emb]
  f16* spare   = take(2048 * 512);      // att_d tail
  f16* h_i1b   = take(2048 * 1024);     // DEDICATED: h_i1 (must not alias att_d
                                        //  — i1 runs concurrently with uf!)
  float* Pbuf  = (float*)take(8 * 1024 * 1024);   // 16 MB fp32 partials
  (void)spare;
  f16* att_d = big;                     // 2048x4096 spans [big|Xc|spare]
  f16* h_u1 = big;                      // 2048x2048 (att_d dead after G1)
  f16* h_m1 = big;                      // 2048x1024 (h_u1 dead after G3)
  f16* h_m2 = uf_h;                     // 2048x512  (uf dead after G2)
  f16* h_m3 = cand_h;                   // 2048x256  (cand_h dead after G1)

  dim3 blk(256);

  // 0. attention logits + dense fp16 attention matrix
  k_rs<<<dim3(In / 4), blk, 0, stream>>>(rated, att_w, rs);
  k_att<<<dim3(Bn), blk, 0, stream>>>(um, rs, att_d);

  // 1. weight prep
  k_transpose_f2h<<<dim3( 512/32, 4096/32), blk, 0, stream>>>(rated, t_rated, 4096, 512);
  k_transpose_f2h<<<dim3(1024/32,  512/32), blk, 0, stream>>>(iw1, t_iw1,  512, 1024);
  k_transpose_f2h<<<dim3( 512/32, 1024/32), blk, 0, stream>>>(iw2, t_iw2, 1024,  512);
  k_transpose_f2h<<<dim3(2048/32,  512/32), blk, 0, stream>>>(uw1, t_uw1,  512, 2048);
  k_transpose_f2h<<<dim3(1024/32, 2048/32), blk, 0, stream>>>(uw2, t_uw2, 2048, 1024);
  k_transpose_f2h<<<dim3(1024/32, 1536/32), blk, 0, stream>>>(mw1, t_mw1, 1536, 1024);
  k_transpose_f2h<<<dim3( 512/32, 1024/32), blk, 0, stream>>>(mw2, t_mw2, 1024,  512);
  k_transpose_f2h<<<dim3( 256/32,  512/32), blk, 0, stream>>>(mw3, t_mw3,  512,  256);
  k_cast_f2h<<<dim3(Bn * Dn / 1024), blk, 0, stream>>>(cand, cand_h, Bn * Dn);

  GemmDesc dUF = { att_d, t_rated, nullptr, nullptr, Pbuf, 512, 4096, 1024, 512, 8, 0 };
  GemmDesc dI1 = { cand_h, t_iw1, ib1, h_i1b, nullptr, 1024, 512, 512, 1024, 16, 1 };
  GemmDesc dU1 = { uf_h, t_uw1, ub1, h_u1, nullptr, 2048, 512, 512, 2048, 32, 1 };
  GemmDesc dI2 = { h_i1b, t_iw2, ib2, Xc, nullptr, 512, 1024, 1024, 1536, 8, 1 };
  GemmDesc dU2 = { h_u1, t_uw2, nullptr, nullptr, Pbuf, 1024, 2048, 1024, 1536, 16, 1 };
  GemmDesc dM1 = { Xc, t_mw1, nullptr, nullptr, Pbuf, 1024, 1536, 768, 1024, 16, 1 };
  GemmDesc dM2 = { h_m1, t_mw2, nullptr, nullptr, Pbuf, 512, 1024, 256, 512, 8, 1 };
  GemmDesc dM3 = { h_m2, t_mw3, nullptr, nullptr, Pbuf, 256, 512, 128, 256, 4, 1 };

  // G1: user_feat GEMM (S=4, 1024 wg) + item MLP layer 1 (512 wg)
  k_mgemm<<<dim3(1536), blk, 0, stream>>>(dUF, dI1, 1024);
  k_reduce<<<dim3(512), blk, 0, stream>>>(Pbuf, 4, 2048 * 512, 512, nullptr, 0, uf_h, 512);

  // G2: user MLP layer 1 (1024 wg) + item MLP layer 2 (256 wg)
  k_mgemm<<<dim3(1280), blk, 0, stream>>>(dU1, dI2, 1024);

  // G3: user MLP layer 2 (S=2, 1024 wg)
  k_mgemm<<<dim3(1024), blk, 0, stream>>>(dU2, dU2, 1024);
  k_reduce<<<dim3(1024), blk, 0, stream>>>(Pbuf, 2, 2048 * 1024, 1024, ub2, 1, Xc + 512, 1536);

  // G4: merge layer 1 (S=2, 1024 wg)
  k_mgemm<<<dim3(1024), blk, 0, stream>>>(dM1, dM1, 1024);
  k_reduce<<<dim3(1024), blk, 0, stream>>>(Pbuf, 2, 2048 * 1024, 1024, mb1, 1, h_m1, 1024);

  // G5: merge layer 2 (S=4, 1024 wg)
  k_mgemm<<<dim3(1024), blk, 0, stream>>>(dM2, dM2, 1024);
  k_reduce<<<dim3(512), blk, 0, stream>>>(Pbuf, 4, 2048 * 512, 512, mb2, 1, h_m2, 512);

  // G6: merge layer 3 (S=4, 512 wg)
  k_mgemm<<<dim3(512), blk, 0, stream>>>(dM3, dM3, 512);
  k_reduce<<<dim3(256), blk, 0, stream>>>(Pbuf, 4, 2048 * 256, 256, mb3, 1, h_m3, 256);

  // final projection (fp32 out)
  k_final<<<dim3(Bn / 4), blk, 0, stream>>>(h_m3, mw4, mb4, out);
}